// Round 9
// baseline (49.668 us; speedup 1.0000x reference)
//
#include <hip/hip_runtime.h>

#define FT 1.0f
#define MAGIC 0x5CA1AB1E

typedef float fvec4 __attribute__((ext_vector_type(4)));
typedef float fvec2 __attribute__((ext_vector_type(2)));

// ============================================================================
// Fused single-launch kernel, specialized S=2048, T=512, C=512, block=256.
// Row blocks (bid < B): bit-exact scan pipeline (verified rounds 1-8), then
// publish + agent-scope release flag. Gather blocks: acquire-spin on their
// row's flag, then feature gather + delay + dur.
// Deadlock-free by capacity: 17B=544 blocks <= 4 blocks/CU * 256 CUs = 1024
// (launch_bounds(256,4) caps VGPR<=128; LDS 20.7KB -> 7/CU).
// ============================================================================
__global__ __launch_bounds__(256, 4) void cif_fused_kernel(
    const float* __restrict__ inp, const float* __restrict__ iw,
    const unsigned char* __restrict__ mask, const int* __restrict__ tlen,
    float* __restrict__ o_out, float* __restrict__ o_delay, float* __restrict__ o_dur,
    float* __restrict__ o_wsum, float* __restrict__ o_rw, float* __restrict__ o_lw,
    int* __restrict__ a_ws, int* __restrict__ hist_g, int* __restrict__ hdr_g,
    int* __restrict__ flags, int B)
{
  constexpr int S = 2048, T = 512, C = 512, NT = 256;
  constexpr int half = S / 2;
  extern __shared__ float smem[];
  const int bid = blockIdx.x, tid = threadIdx.x;

  if (bid < B) {
    // ------------------------------ ROW PATH ------------------------------
    const int b = bid;
    float* w    = smem;                                  // 2048
    float* lv2  = smem + S;                              // 2048
    float* red  = smem + 2 * S;                          // 64
    int*   hist = (int*)(smem + 2 * S + 64);             // 513
    int*   aa   = (int*)(smem + 2 * S + 64 + (T + 1));   // 513
    __shared__ int s_alen;
    const float* iwr = iw + (size_t)b * S;
    const unsigned char* mr = mask + (size_t)b * S;
    const int tl = tlen[b];

    if (tid == 0) s_alen = 0;

    // 1. clip + mask, audio_len (per-wave int reduce, order-free)
    int myal = 0;
#pragma unroll
    for (int s = tid; s < S; s += NT) {
      float v = iwr[s];
      v = fminf(fmaxf(v, 0.0f), 1.0f);
      if (mr[s]) v = 0.0f; else myal++;
      w[s] = v;
    }
#pragma unroll
    for (int off = 32; off >= 1; off >>= 1) myal += __shfl_down(myal, off);
    __syncthreads();                   // B1
    if ((tid & 63) == 0) atomicAdd(&s_alen, myal);

    // 2. wave 0: w_sum (16 strided lanes, x8-unrolled ordered chain + tree);
    //    waves 1-3: init aa + hist
    if (tid < 64) {
      if (tid < 16) {
        float acc = 0.0f;
        int i = tid;
        for (; i + 112 < S; i += 128) {
          float v0 = w[i],      v1 = w[i + 16], v2 = w[i + 32], v3 = w[i + 48];
          float v4 = w[i + 64], v5 = w[i + 80], v6 = w[i + 96], v7 = w[i + 112];
          acc = acc + v0; acc = acc + v1; acc = acc + v2; acc = acc + v3;
          acc = acc + v4; acc = acc + v5; acc = acc + v6; acc = acc + v7;
        }
        for (; i < S; i += 16) acc = acc + w[i];
        red[tid] = acc;
      }
      __builtin_amdgcn_wave_barrier();
      if (tid < 8) red[tid] = red[tid] + red[tid + 8];
      __builtin_amdgcn_wave_barrier();
      if (tid < 4) red[tid] = red[tid] + red[tid + 4];
      __builtin_amdgcn_wave_barrier();
      if (tid < 2) red[tid] = red[tid] + red[tid + 2];
      __builtin_amdgcn_wave_barrier();
      if (tid == 0) red[0] = red[0] + red[1];
    } else {
#pragma unroll
      for (int i = tid - 64; i <= T; i += NT - 64) { aa[i] = (i == 0) ? -1 : S; hist[i] = 0; }
    }
    __syncthreads();                   // B2
    const float wsum = red[0];
    if (tid == 0) o_wsum[b] = wsum;
    const float scale = (FT * (float)tl + 1e-4f) / wsum;

    // 3. up-sweep level 1 fused with scaling
#pragma unroll
    for (int i = tid; i < half; i += NT) {
      float sv0 = w[2 * i] * scale, sv1 = w[2 * i + 1] * scale;
      w[2 * i] = sv0; w[2 * i + 1] = sv1;
      lv2[i] = sv0 + sv1;
    }
    __syncthreads();                   // B3
    // up-sweep sizes 512,256,128
#pragma unroll
    for (int k = 2; k <= 4; ++k) {
      int szk = S >> k;
      int dst = S - 2 * szk, src = S - 4 * szk;
#pragma unroll
      for (int i = tid; i < szk; i += NT)
        lv2[dst + i] = lv2[src + 2 * i] + lv2[src + 2 * i + 1];
      __syncthreads();                 // B4,B5,B6
    }
    // wave 0: up 64..1, down 2..128
    if (tid < 64) {
#pragma unroll
      for (int szk = 64; szk >= 1; szk >>= 1) {
        int dst = S - 2 * szk, src = S - 4 * szk;
        for (int i = tid; i < szk; i += 64)
          lv2[dst + i] = lv2[src + 2 * i] + lv2[src + 2 * i + 1];
        __builtin_amdgcn_wave_barrier();
      }
#pragma unroll
      for (int szk = 2; szk <= 128; szk <<= 1) {
        int ok = S - 2 * szk, ok1 = S - szk;
        for (int j = tid; j < szk; j += 64) {
          if (j == 0) continue;
          if (j & 1) lv2[ok + j] = lv2[ok1 + (j >> 1)];
          else       lv2[ok + j] = lv2[ok1 + (j >> 1) - 1] + lv2[ok + j];
        }
        __builtin_amdgcn_wave_barrier();
      }
    }
    __syncthreads();                   // B7
    // down-sweep sizes 256,512,1024
#pragma unroll
    for (int szk = 256; szk <= half; szk <<= 1) {
      int ok = S - 2 * szk, ok1 = S - szk;
#pragma unroll
      for (int j = tid; j < szk; j += NT) {
        if (j == 0) continue;
        if (j & 1) lv2[ok + j] = lv2[ok1 + (j >> 1)];
        else       lv2[ok + j] = lv2[ok1 + (j >> 1) - 1] + lv2[ok + j];
      }
      __syncthreads();                 // B8,B9,B10
    }

    // 6. final level fused with per-frame phase (csum in registers)
    const size_t bS = (size_t)b * S;
#pragma unroll
    for (int i = tid; i < half; i += NT) {
      float e0 = w[2 * i], e1 = w[2 * i + 1];
      float p  = (i == 0) ? 0.0f : lv2[i - 1];
      float c0 = (i == 0) ? e0 : (p + e0);
      float c1 = lv2[i];
      int li0 = (i == 0) ? 0 : min(max((int)floorf(p), 0), T);
      int ri0 = min(max((int)floorf(c0), 0), T);
      int li1 = ri0;
      int ri1 = min(max((int)floorf(c1), 0), T);
      int n0 = ri0 - li0, n1 = ri1 - li1;
      float rw0 = (n0 > 0) ? (c0 - (float)ri0 * FT) : 0.0f;
      float rw1 = (n1 > 0) ? (c1 - (float)ri1 * FT) : 0.0f;
      float lw0 = (e0 - rw0) - (float)max(n0 - 1, 0) * FT;
      float lw1 = (e1 - rw1) - (float)max(n1 - 1, 0) * FT;
      *reinterpret_cast<fvec2*>(&o_rw[bS + 2 * i]) = fvec2{rw0, rw1};
      *reinterpret_cast<fvec2*>(&o_lw[bS + 2 * i]) = fvec2{lw0, lw1};
      int p0 = min((int)rintf(c0), tl);
      int p1 = min((int)rintf(c1), tl);
      if (p0 == p1) atomicAdd(&hist[p0], 2);
      else { atomicAdd(&hist[p0], 1); atomicAdd(&hist[p1], 1); }
      if (n0 > 0) aa[ri0] = 2 * i;
      if (n1 > 0) aa[ri1] = 2 * i + 1;
    }
    __syncthreads();                   // B11

    // 7. publish firing table + histogram + header
#pragma unroll
    for (int i = tid; i <= T; i += NT) {
      a_ws[(size_t)b * (T + 1) + i]   = aa[i];
      hist_g[(size_t)b * (T + 1) + i] = hist[i];
    }
    if (tid == 0) {
      int seq0 = min((int)rintf(w[0]), tl);
      int m = tl - seq0;
      int L = (m >= tl) ? m : m + 1;
      int adj = s_alen - (S - hist[tl]);
      hdr_g[b * 4 + 0] = seq0; hdr_g[b * 4 + 1] = m;
      hdr_g[b * 4 + 2] = L;    hdr_g[b * 4 + 3] = adj;
    }
    // release: every thread fences its own global writes, barrier establishes
    // intra-block HB, then tid0 publishes with agent-scope release.
    __threadfence();
    __syncthreads();                   // B12
    if (tid == 0)
      __hip_atomic_store(&flags[b], MAGIC, __ATOMIC_RELEASE, __HIP_MEMORY_SCOPE_AGENT);

  } else {
    // ----------------------------- GATHER PATH -----------------------------
    const int gb = bid - B;
    const int b  = gb >> 4;            // 16 gather blocks per row
    const int t0 = (gb & 15) << 5;     // 32 bins per block
    int* sm_b = (int*)smem;            // 33 boundary ints
    __shared__ int sm_hdr[4];

    if (tid == 0) {
      while (__hip_atomic_load(&flags[b], __ATOMIC_ACQUIRE, __HIP_MEMORY_SCOPE_AGENT) != MAGIC)
        __builtin_amdgcn_s_sleep(8);
    }
    __syncthreads();
    if (tid < 33) sm_b[tid] = a_ws[(size_t)b * (T + 1) + t0 + tid];
    if (tid >= 64 && tid < 68) sm_hdr[tid - 64] = hdr_g[b * 4 + (tid - 64)];
    __syncthreads();

    const size_t bS = (size_t)b * S;
    const int g  = tid >> 7;           // two bins processed concurrently
    const int c4 = (tid & 127) * 4;

#pragma unroll
    for (int j = 0; j < 16; ++j) {
      const int t  = t0 + 2 * j + g;
      const int st = sm_b[2 * j + g];
      const int en = min(sm_b[2 * j + g + 1], S - 1);
      fvec4 acc = (fvec4)0.0f;
      float d = 0.0f;
      for (int s = (st < 0 ? 0 : st); s <= en; ++s) {
        const float coeff = (s == st) ? o_rw[bS + s] : o_lw[bS + s];
        d = d + (coeff * (float)(s + 1)) / FT;
        const fvec4 v = *reinterpret_cast<const fvec4*>(inp + (bS + s) * (size_t)C + c4);
        acc += coeff * v;
      }
      __builtin_nontemporal_store(acc,
          reinterpret_cast<fvec4*>(o_out + ((size_t)b * T + t) * (size_t)C + c4));
      if ((tid & 127) == 0)
        __builtin_nontemporal_store(d, &o_delay[(size_t)b * T + t]);
    }

    if (tid < 32) {
      const int t = t0 + tid;
      const int seq0 = sm_hdr[0], m = sm_hdr[1], L = sm_hdr[2], adj = sm_hdr[3];
      int dv = (t < m) ? hist_g[(size_t)b * (T + 1) + seq0 + t] : 0;
      if (t == L - 1) dv += adj;
      __builtin_nontemporal_store((float)dv, &o_dur[(size_t)b * T + t]);
    }
  }
}

// ============================================================================
// Generic fallback (round-8 two-kernel path) for non-specialized shapes.
// ============================================================================
__global__ __launch_bounds__(512) void cif_row_generic(
    const float* __restrict__ iw, const unsigned char* __restrict__ mask,
    const int* __restrict__ tlen,
    float* __restrict__ o_wsum, float* __restrict__ o_rw, float* __restrict__ o_lw,
    int* __restrict__ a_ws, int* __restrict__ hist_g, int* __restrict__ hdr_g,
    int S, int T)
{
  extern __shared__ float smem[];
  float* w    = smem;
  float* lv2  = smem + S;
  float* red  = smem + 2 * S;
  int*   hist = (int*)(smem + 2 * S + 64);
  int*   aa   = (int*)(smem + 2 * S + 64 + (T + 1));
  __shared__ int s_alen;

  const int b = blockIdx.x, tid = threadIdx.x, nt = blockDim.x;
  const float* iwr = iw + (size_t)b * S;
  const unsigned char* mr = mask + (size_t)b * S;
  const int tl = tlen[b];
  const int half = S >> 1;

  if (tid == 0) s_alen = 0;
  int myal = 0;
  for (int s = tid; s < S; s += nt) {
    float v = iwr[s];
    v = fminf(fmaxf(v, 0.0f), 1.0f);
    if (mr[s]) v = 0.0f; else myal++;
    w[s] = v;
  }
  __syncthreads();
  atomicAdd(&s_alen, myal);
  if (tid < 64) {
    if (tid < 16) {
      float acc = 0.0f;
      for (int i = tid; i < S; i += 16) acc = acc + w[i];
      red[tid] = acc;
    }
    __builtin_amdgcn_wave_barrier();
    if (tid < 8) red[tid] = red[tid] + red[tid + 8];
    __builtin_amdgcn_wave_barrier();
    if (tid < 4) red[tid] = red[tid] + red[tid + 4];
    __builtin_amdgcn_wave_barrier();
    if (tid < 2) red[tid] = red[tid] + red[tid + 2];
    __builtin_amdgcn_wave_barrier();
    if (tid == 0) red[0] = red[0] + red[1];
  } else {
    for (int i = tid - 64; i <= T; i += nt - 64) { aa[i] = (i == 0) ? -1 : S; hist[i] = 0; }
  }
  __syncthreads();
  const float wsum = red[0];
  if (tid == 0) o_wsum[b] = wsum;
  const float scale = (FT * (float)tl + 1e-4f) / wsum;
  for (int i = tid; i < half; i += nt) {
    float sv0 = w[2 * i] * scale, sv1 = w[2 * i + 1] * scale;
    w[2 * i] = sv0; w[2 * i + 1] = sv1;
    lv2[i] = sv0 + sv1;
  }
  __syncthreads();
  for (int k = 2; k <= 4; ++k) {
    int szk = S >> k;
    int dst = S - 2 * szk, src = S - 4 * szk;
    for (int i = tid; i < szk; i += nt)
      lv2[dst + i] = lv2[src + 2 * i] + lv2[src + 2 * i + 1];
    __syncthreads();
  }
  if (tid < 64) {
    for (int szk = S >> 5; szk >= 1; szk >>= 1) {
      int dst = S - 2 * szk, src = S - 4 * szk;
      for (int i = tid; i < szk; i += 64)
        lv2[dst + i] = lv2[src + 2 * i] + lv2[src + 2 * i + 1];
      __builtin_amdgcn_wave_barrier();
    }
    for (int szk = 2; szk <= 128; szk <<= 1) {
      int ok = S - 2 * szk, ok1 = S - szk;
      for (int j = tid; j < szk; j += 64) {
        if (j == 0) continue;
        if (j & 1) lv2[ok + j] = lv2[ok1 + (j >> 1)];
        else       lv2[ok + j] = lv2[ok1 + (j >> 1) - 1] + lv2[ok + j];
      }
      __builtin_amdgcn_wave_barrier();
    }
  }
  __syncthreads();
  for (int szk = 256; szk <= half; szk <<= 1) {
    int ok = S - 2 * szk, ok1 = S - szk;
    for (int j = tid; j < szk; j += nt) {
      if (j == 0) continue;
      if (j & 1) lv2[ok + j] = lv2[ok1 + (j >> 1)];
      else       lv2[ok + j] = lv2[ok1 + (j >> 1) - 1] + lv2[ok + j];
    }
    __syncthreads();
  }
  const size_t bS = (size_t)b * S;
  for (int i = tid; i < half; i += nt) {
    float e0 = w[2 * i], e1 = w[2 * i + 1];
    float p  = (i == 0) ? 0.0f : lv2[i - 1];
    float c0 = (i == 0) ? e0 : (p + e0);
    float c1 = lv2[i];
    int li0 = (i == 0) ? 0 : min(max((int)floorf(p), 0), T);
    int ri0 = min(max((int)floorf(c0), 0), T);
    int li1 = ri0;
    int ri1 = min(max((int)floorf(c1), 0), T);
    int n0 = ri0 - li0, n1 = ri1 - li1;
    float rw0 = (n0 > 0) ? (c0 - (float)ri0 * FT) : 0.0f;
    float rw1 = (n1 > 0) ? (c1 - (float)ri1 * FT) : 0.0f;
    float lw0 = (e0 - rw0) - (float)max(n0 - 1, 0) * FT;
    float lw1 = (e1 - rw1) - (float)max(n1 - 1, 0) * FT;
    *reinterpret_cast<fvec2*>(&o_rw[bS + 2 * i]) = fvec2{rw0, rw1};
    *reinterpret_cast<fvec2*>(&o_lw[bS + 2 * i]) = fvec2{lw0, lw1};
    int p0 = min((int)rintf(c0), tl);
    int p1 = min((int)rintf(c1), tl);
    if (p0 == p1) atomicAdd(&hist[p0], 2);
    else { atomicAdd(&hist[p0], 1); atomicAdd(&hist[p1], 1); }
    if (n0 > 0) aa[ri0] = 2 * i;
    if (n1 > 0) aa[ri1] = 2 * i + 1;
  }
  __syncthreads();
  for (int i = tid; i <= T; i += nt) {
    a_ws[(size_t)b * (T + 1) + i]   = aa[i];
    hist_g[(size_t)b * (T + 1) + i] = hist[i];
  }
  if (tid == 0) {
    int seq0 = min((int)rintf(w[0]), tl);
    int m = tl - seq0;
    int L = (m >= tl) ? m : m + 1;
    int adj = s_alen - (S - hist[tl]);
    hdr_g[b * 4 + 0] = seq0; hdr_g[b * 4 + 1] = m;
    hdr_g[b * 4 + 2] = L;    hdr_g[b * 4 + 3] = adj;
  }
}

#define KBINS 8
__global__ __launch_bounds__(128) void cif_gather_generic(const float* __restrict__ in,
    const float* __restrict__ rw, const float* __restrict__ lw,
    const int* __restrict__ a_ws, const int* __restrict__ hist_g,
    const int* __restrict__ hdr_g,
    float* __restrict__ out, float* __restrict__ o_delay, float* __restrict__ o_dur,
    int S, int T, int C)
{
  const int b = blockIdx.y;
  const int t0 = blockIdx.x * KBINS;
  const int* ab = a_ws + (size_t)b * (T + 1);
  const size_t bS = (size_t)b * S;
  const int c4 = threadIdx.x * 4;

  int bound[KBINS + 1];
#pragma unroll
  for (int k = 0; k <= KBINS; ++k) bound[k] = ab[min(t0 + k, T)];
#pragma unroll
  for (int k = 0; k < KBINS; ++k) {
    const int t = t0 + k;
    if (t >= T) break;
    const int st = bound[k];
    const int en = min(bound[k + 1], S - 1);
    fvec4 acc = (fvec4)0.0f;
    float d = 0.0f;
    for (int s = (st < 0 ? 0 : st); s <= en; ++s) {
      const float coeff = (s == st) ? rw[bS + s] : lw[bS + s];
      d = d + (coeff * (float)(s + 1)) / FT;
      const fvec4 v = *reinterpret_cast<const fvec4*>(in + (bS + s) * (size_t)C + c4);
      acc += coeff * v;
    }
    __builtin_nontemporal_store(acc,
        reinterpret_cast<fvec4*>(out + ((size_t)b * T + t) * (size_t)C + c4));
    if (threadIdx.x == 0)
      __builtin_nontemporal_store(d, &o_delay[(size_t)b * T + t]);
  }
  if (threadIdx.x < KBINS) {
    const int t = t0 + threadIdx.x;
    if (t < T) {
      const int seq0 = hdr_g[b * 4 + 0];
      const int m    = hdr_g[b * 4 + 1];
      const int L    = hdr_g[b * 4 + 2];
      const int adj  = hdr_g[b * 4 + 3];
      int dv = (t < m) ? hist_g[(size_t)b * (T + 1) + seq0 + t] : 0;
      if (t == L - 1) dv += adj;
      __builtin_nontemporal_store((float)dv, &o_dur[(size_t)b * T + t]);
    }
  }
}

extern "C" void kernel_launch(void* const* d_in, const int* in_sizes, int n_in,
                              void* d_out, int out_size, void* d_ws, size_t ws_size,
                              hipStream_t stream)
{
  const float* inp = (const float*)d_in[0];
  const float* iw  = (const float*)d_in[1];
  const unsigned char* mask = (const unsigned char*)d_in[2];
  const int* tl = (const int*)d_in[3];
  const int B = in_sizes[3];
  const int S = in_sizes[1] / B;
  const int C = in_sizes[0] / in_sizes[1];
  const long long T = ((long long)out_size - B - 2LL * B * S) / ((long long)B * C + 2LL * B);

  float* o = (float*)d_out;
  float* o_out   = o;
  float* o_delay = o_out + (size_t)B * T * C;
  float* o_dur   = o_delay + (size_t)B * T;
  float* o_wsum  = o_dur + (size_t)B * T;
  float* o_rw    = o_wsum + B;
  float* o_lw    = o_rw + (size_t)B * S;

  int* a_ws   = (int*)d_ws;                      // B*(T+1)
  int* hist_g = a_ws + (size_t)B * (T + 1);      // B*(T+1)
  int* hdr_g  = hist_g + (size_t)B * (T + 1);    // B*4
  int* flags  = hdr_g + (size_t)B * 4;           // B

  size_t smem = (size_t)(2 * S + 64) * sizeof(float) + 2 * (size_t)(T + 1) * sizeof(int);

  if (S == 2048 && T == 512 && C == 512 && B <= 60) {
    const int nblk = B + B * 16;   // B row blocks + 16 gather blocks per row
    hipLaunchKernelGGL(cif_fused_kernel, dim3(nblk), dim3(256), smem, stream,
                       inp, iw, mask, tl, o_out, o_delay, o_dur,
                       o_wsum, o_rw, o_lw, a_ws, hist_g, hdr_g, flags, B);
  } else {
    hipLaunchKernelGGL(cif_row_generic, dim3(B), dim3(512), smem, stream,
                       iw, mask, tl, o_wsum, o_rw, o_lw, a_ws, hist_g, hdr_g, S, (int)T);
    dim3 g2((unsigned)((T + KBINS - 1) / KBINS), (unsigned)B);
    hipLaunchKernelGGL(cif_gather_generic, g2, dim3(C / 4), 0, stream,
                       inp, o_rw, o_lw, a_ws, hist_g, hdr_g, o_out, o_delay, o_dur,
                       S, (int)T, C);
  }
}

// Round 10
// 39.906 us; speedup vs baseline: 1.2446x; 1.2446x over previous
//
#include <hip/hip_runtime.h>

#define FT 1.0f

typedef float fvec4 __attribute__((ext_vector_type(4)));
typedef float fvec2 __attribute__((ext_vector_type(2)));

// One block per batch row. Bit-exact vs jax-CPU (verified rounds 1-8):
//  - w_sum: 16 strided lanes + halving tree (XLA:CPU vectorized reduce)
//  - cumsum: lax.associative_scan recursive decomposition
// Round 10: revert round-9 fusion (occupancy collapse: 544-block grid -> 23%
// occupancy, 196us dispatch). Round-8 two-kernel structure; single change:
// KBINS 8->4 doubles gather grid to 4096 blocks -> 32 waves/CU (thread cap)
// during the gather phase for better latency hiding.
template<int SC, int TC>
__global__ __launch_bounds__(512) void cif_row_kernel(
    const float* __restrict__ iw, const unsigned char* __restrict__ mask,
    const int* __restrict__ tlen,
    float* __restrict__ o_wsum, float* __restrict__ o_rw, float* __restrict__ o_lw,
    int* __restrict__ a_ws, int* __restrict__ hist_g, int* __restrict__ hdr_g,
    int S_rt, int T_rt)
{
  const int S = (SC > 0) ? SC : S_rt;
  const int T = (TC > 0) ? TC : T_rt;

  extern __shared__ float smem[];
  float* w    = smem;                 // S floats: clipped w, then scaled w
  float* lv2  = smem + S;             // S floats: levels 1..K (level k at S-2*(S>>k))
  float* red  = smem + 2 * S;         // 64 floats
  int*   hist = (int*)(smem + 2 * S + 64);            // T+1 ints
  int*   aa   = (int*)(smem + 2 * S + 64 + (T + 1));  // T+1 ints
  __shared__ int s_alen;

  const int b = blockIdx.x, tid = threadIdx.x;
  const int nt = 512;
  const float* iwr = iw + (size_t)b * S;
  const unsigned char* mr = mask + (size_t)b * S;
  const int tl = tlen[b];
  const int half = S >> 1;

  if (tid == 0) s_alen = 0;

  // 1. clip + mask, audio_len
  int myal = 0;
#pragma unroll
  for (int s = tid; s < S; s += nt) {
    float v = iwr[s];
    v = fminf(fmaxf(v, 0.0f), 1.0f);
    if (mr[s]) v = 0.0f; else myal++;
    w[s] = v;
  }
  // per-wave integer reduce (order-free), one atomic per wave
  #pragma unroll
  for (int off = 32; off >= 1; off >>= 1) myal += __shfl_down(myal, off);
  __syncthreads();                     // B1: w[] + s_alen init visible
  if ((tid & 63) == 0) atomicAdd(&s_alen, myal);

  // 2. wave 0: w_sum (16 strided lanes, x8-unrolled ordered chain + halving
  //    tree); waves 1-7: init aa+hist
  if (tid < 64) {
    if (tid < 16) {
      float acc = 0.0f;
      int i = tid;
      for (; i + 112 < S; i += 128) {
        float v0 = w[i],      v1 = w[i + 16], v2 = w[i + 32], v3 = w[i + 48];
        float v4 = w[i + 64], v5 = w[i + 80], v6 = w[i + 96], v7 = w[i + 112];
        acc = acc + v0; acc = acc + v1; acc = acc + v2; acc = acc + v3;
        acc = acc + v4; acc = acc + v5; acc = acc + v6; acc = acc + v7;
      }
      for (; i < S; i += 16) acc = acc + w[i];
      red[tid] = acc;
    }
    __builtin_amdgcn_wave_barrier();
    if (tid < 8) red[tid] = red[tid] + red[tid + 8];
    __builtin_amdgcn_wave_barrier();
    if (tid < 4) red[tid] = red[tid] + red[tid + 4];
    __builtin_amdgcn_wave_barrier();
    if (tid < 2) red[tid] = red[tid] + red[tid + 2];
    __builtin_amdgcn_wave_barrier();
    if (tid == 0) red[0] = red[0] + red[1];
  } else {
#pragma unroll
    for (int i = tid - 64; i <= T; i += nt - 64) { aa[i] = (i == 0) ? -1 : S; hist[i] = 0; }
  }
  __syncthreads();                     // B2
  const float wsum = red[0];
  if (tid == 0) o_wsum[b] = wsum;
  const float scale = (FT * (float)tl + 1e-4f) / wsum;

  // 3. up-sweep level 1 fused with scaling (w becomes scaled in-place)
#pragma unroll
  for (int i = tid; i < half; i += nt) {
    float sv0 = w[2 * i] * scale, sv1 = w[2 * i + 1] * scale;
    w[2 * i] = sv0; w[2 * i + 1] = sv1;
    lv2[i] = sv0 + sv1;
  }
  __syncthreads();                     // B3
  // up-sweep k=2..4 (sizes 512,256,128), multi-wave
#pragma unroll
  for (int k = 2; k <= 4; ++k) {
    int szk = S >> k;
    int dst = S - 2 * szk, src = S - 4 * szk;
#pragma unroll
    for (int i = tid; i < szk; i += nt)
      lv2[dst + i] = lv2[src + 2 * i] + lv2[src + 2 * i + 1];
    __syncthreads();                   // B4,B5,B6
  }

  // wave 0 only: up-sweep sizes 64..1, then down-sweep sizes 2..128
  if (tid < 64) {
#pragma unroll
    for (int szk = S >> 5; szk >= 1; szk >>= 1) {
      int dst = S - 2 * szk, src = S - 4 * szk;
      for (int i = tid; i < szk; i += 64)
        lv2[dst + i] = lv2[src + 2 * i] + lv2[src + 2 * i + 1];
      __builtin_amdgcn_wave_barrier();
    }
#pragma unroll
    for (int szk = 2; szk <= 128; szk <<= 1) {
      int ok = S - 2 * szk, ok1 = S - szk;
      for (int j = tid; j < szk; j += 64) {
        if (j == 0) continue;
        if (j & 1) lv2[ok + j] = lv2[ok1 + (j >> 1)];
        else       lv2[ok + j] = lv2[ok1 + (j >> 1) - 1] + lv2[ok + j];
      }
      __builtin_amdgcn_wave_barrier();
    }
  }
  __syncthreads();                     // B7
  // down-sweep sizes 256,512,1024, multi-wave
#pragma unroll
  for (int szk = 256; szk <= (SC > 0 ? (SC >> 1) : half); szk <<= 1) {
    int ok = S - 2 * szk, ok1 = S - szk;
#pragma unroll
    for (int j = tid; j < szk; j += nt) {
      if (j == 0) continue;
      if (j & 1) lv2[ok + j] = lv2[ok1 + (j >> 1)];
      else       lv2[ok + j] = lv2[ok1 + (j >> 1) - 1] + lv2[ok + j];
    }
    __syncthreads();                   // B8,B9,B10
  }

  // 6. final level fused with per-frame phase: csum for frames 2i,2i+1 in
  // registers (adds identical to the down-sweep's), never materialized.
  const size_t bS = (size_t)b * S;
#pragma unroll
  for (int i = tid; i < half; i += nt) {
    float e0 = w[2 * i], e1 = w[2 * i + 1];
    float p  = (i == 0) ? 0.0f : lv2[i - 1];
    float c0 = (i == 0) ? e0 : (p + e0);
    float c1 = lv2[i];
    int li0 = (i == 0) ? 0 : min(max((int)floorf(p), 0), T);
    int ri0 = min(max((int)floorf(c0), 0), T);
    int li1 = ri0;
    int ri1 = min(max((int)floorf(c1), 0), T);
    int n0 = ri0 - li0, n1 = ri1 - li1;
    float rw0 = (n0 > 0) ? (c0 - (float)ri0 * FT) : 0.0f;
    float rw1 = (n1 > 0) ? (c1 - (float)ri1 * FT) : 0.0f;
    float lw0 = (e0 - rw0) - (float)max(n0 - 1, 0) * FT;
    float lw1 = (e1 - rw1) - (float)max(n1 - 1, 0) * FT;
    *reinterpret_cast<fvec2*>(&o_rw[bS + 2 * i]) = fvec2{rw0, rw1};
    *reinterpret_cast<fvec2*>(&o_lw[bS + 2 * i]) = fvec2{lw0, lw1};
    int p0 = min((int)rintf(c0), tl);
    int p1 = min((int)rintf(c1), tl);
    if (p0 == p1) atomicAdd(&hist[p0], 2);
    else { atomicAdd(&hist[p0], 1); atomicAdd(&hist[p1], 1); }
    if (n0 > 0) aa[ri0] = 2 * i;
    if (n1 > 0) aa[ri1] = 2 * i + 1;
  }
  __syncthreads();                     // B11

  // 7. publish firing table + histogram + header for the gather kernel
#pragma unroll
  for (int i = tid; i <= T; i += nt) {
    a_ws[(size_t)b * (T + 1) + i]   = aa[i];
    hist_g[(size_t)b * (T + 1) + i] = hist[i];
  }
  if (tid == 0) {
    int seq0 = min((int)rintf(w[0]), tl);  // round(csum[0]) capped
    int m = tl - seq0;                     // monotone +1 steps -> telescopes
    int L = (m >= tl) ? m : m + 1;
    int adj = s_alen - (S - hist[tl]);     // alen - sum(dur[t<m])
    hdr_g[b * 4 + 0] = seq0; hdr_g[b * 4 + 1] = m;
    hdr_g[b * 4 + 2] = L;    hdr_g[b * 4 + 3] = adj;
  }
}

// Gather + delay + dur. KBINS bins per block; boundary frames shared between
// consecutive bins hit L1/L2 (normal loads — NT loads regressed in round 6).
// delay accumulates the same coefficients the feature gather loads, in the
// same order (right term first, then ascending lefts) — bit-identical.
// KBINS=4: 4096 blocks -> 32 waves/CU (vs 16 at KBINS=8) for latency hiding.
#define KBINS 4
__global__ __launch_bounds__(128) void cif_gather_kernel(const float* __restrict__ in,
    const float* __restrict__ rw, const float* __restrict__ lw,
    const int* __restrict__ a_ws, const int* __restrict__ hist_g,
    const int* __restrict__ hdr_g,
    float* __restrict__ out, float* __restrict__ o_delay, float* __restrict__ o_dur,
    int S, int T, int C)
{
  const int b = blockIdx.y;
  const int t0 = blockIdx.x * KBINS;
  const int* ab = a_ws + (size_t)b * (T + 1);
  const size_t bS = (size_t)b * S;
  const int c4 = threadIdx.x * 4;

  int bound[KBINS + 1];
#pragma unroll
  for (int k = 0; k <= KBINS; ++k) bound[k] = ab[min(t0 + k, T)];

#pragma unroll
  for (int k = 0; k < KBINS; ++k) {
    const int t = t0 + k;
    if (t >= T) break;
    const int st = bound[k];
    const int en = min(bound[k + 1], S - 1);
    fvec4 acc = (fvec4)0.0f;
    float d = 0.0f;
    for (int s = (st < 0 ? 0 : st); s <= en; ++s) {
      const float coeff = (s == st) ? rw[bS + s] : lw[bS + s];
      d = d + (coeff * (float)(s + 1)) / FT;
      const fvec4 v = *reinterpret_cast<const fvec4*>(in + (bS + s) * (size_t)C + c4);
      acc += coeff * v;
    }
    __builtin_nontemporal_store(acc,
        reinterpret_cast<fvec4*>(out + ((size_t)b * T + t) * (size_t)C + c4));
    if (threadIdx.x == 0)
      __builtin_nontemporal_store(d, &o_delay[(size_t)b * T + t]);
  }

  // dur for this block's bins (1 thread per bin)
  if (threadIdx.x < KBINS) {
    const int t = t0 + threadIdx.x;
    if (t < T) {
      const int seq0 = hdr_g[b * 4 + 0];
      const int m    = hdr_g[b * 4 + 1];
      const int L    = hdr_g[b * 4 + 2];
      const int adj  = hdr_g[b * 4 + 3];
      int dv = (t < m) ? hist_g[(size_t)b * (T + 1) + seq0 + t] : 0;
      if (t == L - 1) dv += adj;
      __builtin_nontemporal_store((float)dv, &o_dur[(size_t)b * T + t]);
    }
  }
}

extern "C" void kernel_launch(void* const* d_in, const int* in_sizes, int n_in,
                              void* d_out, int out_size, void* d_ws, size_t ws_size,
                              hipStream_t stream)
{
  const float* inp = (const float*)d_in[0];
  const float* iw  = (const float*)d_in[1];
  const unsigned char* mask = (const unsigned char*)d_in[2];
  const int* tl = (const int*)d_in[3];
  const int B = in_sizes[3];
  const int S = in_sizes[1] / B;
  const int C = in_sizes[0] / in_sizes[1];
  const long long T = ((long long)out_size - B - 2LL * B * S) / ((long long)B * C + 2LL * B);

  float* o = (float*)d_out;
  float* o_out   = o;
  float* o_delay = o_out + (size_t)B * T * C;
  float* o_dur   = o_delay + (size_t)B * T;
  float* o_wsum  = o_dur + (size_t)B * T;
  float* o_rw    = o_wsum + B;
  float* o_lw    = o_rw + (size_t)B * S;

  int* a_ws   = (int*)d_ws;                      // B*(T+1)
  int* hist_g = a_ws + (size_t)B * (T + 1);      // B*(T+1)
  int* hdr_g  = hist_g + (size_t)B * (T + 1);    // B*4

  size_t smem = (size_t)(2 * S + 64) * sizeof(float) + 2 * (size_t)(T + 1) * sizeof(int);
  if (S == 2048 && T == 512) {
    hipLaunchKernelGGL((cif_row_kernel<2048, 512>), dim3(B), dim3(512), smem, stream,
                       iw, mask, tl, o_wsum, o_rw, o_lw, a_ws, hist_g, hdr_g, S, (int)T);
  } else {
    hipLaunchKernelGGL((cif_row_kernel<0, 0>), dim3(B), dim3(512), smem, stream,
                       iw, mask, tl, o_wsum, o_rw, o_lw, a_ws, hist_g, hdr_g, S, (int)T);
  }
  dim3 g2((unsigned)((T + KBINS - 1) / KBINS), (unsigned)B);
  hipLaunchKernelGGL(cif_gather_kernel, g2, dim3(C / 4), 0, stream,
                     inp, o_rw, o_lw, a_ws, hist_g, hdr_g, o_out, o_delay, o_dur,
                     S, (int)T, C);
}

// Round 11
// 38.649 us; speedup vs baseline: 1.2851x; 1.0325x over previous
//
#include <hip/hip_runtime.h>

#define FT 1.0f

typedef float fvec4 __attribute__((ext_vector_type(4)));
typedef float fvec2 __attribute__((ext_vector_type(2)));

// One block per batch row. Bit-exact vs jax-CPU (verified rounds 1-10):
//  - w_sum: 16 strided lanes + halving tree (XLA:CPU vectorized reduce)
//  - cumsum: lax.associative_scan recursive decomposition
// Round 11: revert to the measured optimum (round-8 config, KBINS=8).
// A/B history: KBINS=4 -> 39.9us (boundary dupes > latency-hiding gain),
// KBINS=8 -> 38.8us, fused single-launch -> 49.7us (occupancy collapse),
// NT gather loads -> +4us (killed L1 boundary reuse). Gather is BW-saturated.
template<int SC, int TC>
__global__ __launch_bounds__(512) void cif_row_kernel(
    const float* __restrict__ iw, const unsigned char* __restrict__ mask,
    const int* __restrict__ tlen,
    float* __restrict__ o_wsum, float* __restrict__ o_rw, float* __restrict__ o_lw,
    int* __restrict__ a_ws, int* __restrict__ hist_g, int* __restrict__ hdr_g,
    int S_rt, int T_rt)
{
  const int S = (SC > 0) ? SC : S_rt;
  const int T = (TC > 0) ? TC : T_rt;

  extern __shared__ float smem[];
  float* w    = smem;                 // S floats: clipped w, then scaled w
  float* lv2  = smem + S;             // S floats: levels 1..K (level k at S-2*(S>>k))
  float* red  = smem + 2 * S;         // 64 floats
  int*   hist = (int*)(smem + 2 * S + 64);            // T+1 ints
  int*   aa   = (int*)(smem + 2 * S + 64 + (T + 1));  // T+1 ints
  __shared__ int s_alen;

  const int b = blockIdx.x, tid = threadIdx.x;
  const int nt = 512;
  const float* iwr = iw + (size_t)b * S;
  const unsigned char* mr = mask + (size_t)b * S;
  const int tl = tlen[b];
  const int half = S >> 1;

  if (tid == 0) s_alen = 0;

  // 1. clip + mask, audio_len
  int myal = 0;
#pragma unroll
  for (int s = tid; s < S; s += nt) {
    float v = iwr[s];
    v = fminf(fmaxf(v, 0.0f), 1.0f);
    if (mr[s]) v = 0.0f; else myal++;
    w[s] = v;
  }
  // per-wave integer reduce (order-free), one atomic per wave
  #pragma unroll
  for (int off = 32; off >= 1; off >>= 1) myal += __shfl_down(myal, off);
  __syncthreads();                     // B1: w[] + s_alen init visible
  if ((tid & 63) == 0) atomicAdd(&s_alen, myal);

  // 2. wave 0: w_sum (16 strided lanes, x8-unrolled ordered chain + halving
  //    tree); waves 1-7: init aa+hist
  if (tid < 64) {
    if (tid < 16) {
      float acc = 0.0f;
      int i = tid;
      for (; i + 112 < S; i += 128) {
        float v0 = w[i],      v1 = w[i + 16], v2 = w[i + 32], v3 = w[i + 48];
        float v4 = w[i + 64], v5 = w[i + 80], v6 = w[i + 96], v7 = w[i + 112];
        acc = acc + v0; acc = acc + v1; acc = acc + v2; acc = acc + v3;
        acc = acc + v4; acc = acc + v5; acc = acc + v6; acc = acc + v7;
      }
      for (; i < S; i += 16) acc = acc + w[i];
      red[tid] = acc;
    }
    __builtin_amdgcn_wave_barrier();
    if (tid < 8) red[tid] = red[tid] + red[tid + 8];
    __builtin_amdgcn_wave_barrier();
    if (tid < 4) red[tid] = red[tid] + red[tid + 4];
    __builtin_amdgcn_wave_barrier();
    if (tid < 2) red[tid] = red[tid] + red[tid + 2];
    __builtin_amdgcn_wave_barrier();
    if (tid == 0) red[0] = red[0] + red[1];
  } else {
#pragma unroll
    for (int i = tid - 64; i <= T; i += nt - 64) { aa[i] = (i == 0) ? -1 : S; hist[i] = 0; }
  }
  __syncthreads();                     // B2
  const float wsum = red[0];
  if (tid == 0) o_wsum[b] = wsum;
  const float scale = (FT * (float)tl + 1e-4f) / wsum;

  // 3. up-sweep level 1 fused with scaling (w becomes scaled in-place)
#pragma unroll
  for (int i = tid; i < half; i += nt) {
    float sv0 = w[2 * i] * scale, sv1 = w[2 * i + 1] * scale;
    w[2 * i] = sv0; w[2 * i + 1] = sv1;
    lv2[i] = sv0 + sv1;
  }
  __syncthreads();                     // B3
  // up-sweep k=2..4 (sizes 512,256,128), multi-wave
#pragma unroll
  for (int k = 2; k <= 4; ++k) {
    int szk = S >> k;
    int dst = S - 2 * szk, src = S - 4 * szk;
#pragma unroll
    for (int i = tid; i < szk; i += nt)
      lv2[dst + i] = lv2[src + 2 * i] + lv2[src + 2 * i + 1];
    __syncthreads();                   // B4,B5,B6
  }

  // wave 0 only: up-sweep sizes 64..1, then down-sweep sizes 2..128
  if (tid < 64) {
#pragma unroll
    for (int szk = S >> 5; szk >= 1; szk >>= 1) {
      int dst = S - 2 * szk, src = S - 4 * szk;
      for (int i = tid; i < szk; i += 64)
        lv2[dst + i] = lv2[src + 2 * i] + lv2[src + 2 * i + 1];
      __builtin_amdgcn_wave_barrier();
    }
#pragma unroll
    for (int szk = 2; szk <= 128; szk <<= 1) {
      int ok = S - 2 * szk, ok1 = S - szk;
      for (int j = tid; j < szk; j += 64) {
        if (j == 0) continue;
        if (j & 1) lv2[ok + j] = lv2[ok1 + (j >> 1)];
        else       lv2[ok + j] = lv2[ok1 + (j >> 1) - 1] + lv2[ok + j];
      }
      __builtin_amdgcn_wave_barrier();
    }
  }
  __syncthreads();                     // B7
  // down-sweep sizes 256,512,1024, multi-wave
#pragma unroll
  for (int szk = 256; szk <= (SC > 0 ? (SC >> 1) : half); szk <<= 1) {
    int ok = S - 2 * szk, ok1 = S - szk;
#pragma unroll
    for (int j = tid; j < szk; j += nt) {
      if (j == 0) continue;
      if (j & 1) lv2[ok + j] = lv2[ok1 + (j >> 1)];
      else       lv2[ok + j] = lv2[ok1 + (j >> 1) - 1] + lv2[ok + j];
    }
    __syncthreads();                   // B8,B9,B10
  }

  // 6. final level fused with per-frame phase: csum for frames 2i,2i+1 in
  // registers (adds identical to the down-sweep's), never materialized.
  const size_t bS = (size_t)b * S;
#pragma unroll
  for (int i = tid; i < half; i += nt) {
    float e0 = w[2 * i], e1 = w[2 * i + 1];
    float p  = (i == 0) ? 0.0f : lv2[i - 1];
    float c0 = (i == 0) ? e0 : (p + e0);
    float c1 = lv2[i];
    int li0 = (i == 0) ? 0 : min(max((int)floorf(p), 0), T);
    int ri0 = min(max((int)floorf(c0), 0), T);
    int li1 = ri0;
    int ri1 = min(max((int)floorf(c1), 0), T);
    int n0 = ri0 - li0, n1 = ri1 - li1;
    float rw0 = (n0 > 0) ? (c0 - (float)ri0 * FT) : 0.0f;
    float rw1 = (n1 > 0) ? (c1 - (float)ri1 * FT) : 0.0f;
    float lw0 = (e0 - rw0) - (float)max(n0 - 1, 0) * FT;
    float lw1 = (e1 - rw1) - (float)max(n1 - 1, 0) * FT;
    *reinterpret_cast<fvec2*>(&o_rw[bS + 2 * i]) = fvec2{rw0, rw1};
    *reinterpret_cast<fvec2*>(&o_lw[bS + 2 * i]) = fvec2{lw0, lw1};
    int p0 = min((int)rintf(c0), tl);
    int p1 = min((int)rintf(c1), tl);
    if (p0 == p1) atomicAdd(&hist[p0], 2);
    else { atomicAdd(&hist[p0], 1); atomicAdd(&hist[p1], 1); }
    if (n0 > 0) aa[ri0] = 2 * i;
    if (n1 > 0) aa[ri1] = 2 * i + 1;
  }
  __syncthreads();                     // B11

  // 7. publish firing table + histogram + header for the gather kernel
#pragma unroll
  for (int i = tid; i <= T; i += nt) {
    a_ws[(size_t)b * (T + 1) + i]   = aa[i];
    hist_g[(size_t)b * (T + 1) + i] = hist[i];
  }
  if (tid == 0) {
    int seq0 = min((int)rintf(w[0]), tl);  // round(csum[0]) capped
    int m = tl - seq0;                     // monotone +1 steps -> telescopes
    int L = (m >= tl) ? m : m + 1;
    int adj = s_alen - (S - hist[tl]);     // alen - sum(dur[t<m])
    hdr_g[b * 4 + 0] = seq0; hdr_g[b * 4 + 1] = m;
    hdr_g[b * 4 + 2] = L;    hdr_g[b * 4 + 3] = adj;
  }
}

// Gather + delay + dur. KBINS=8 bins per block (measured optimum); boundary
// frames shared between consecutive bins hit L1/L2 (normal loads — NT loads
// regressed in round 6). delay accumulates the same coefficients the feature
// gather loads, in the same order — bit-identical.
#define KBINS 8
__global__ __launch_bounds__(128) void cif_gather_kernel(const float* __restrict__ in,
    const float* __restrict__ rw, const float* __restrict__ lw,
    const int* __restrict__ a_ws, const int* __restrict__ hist_g,
    const int* __restrict__ hdr_g,
    float* __restrict__ out, float* __restrict__ o_delay, float* __restrict__ o_dur,
    int S, int T, int C)
{
  const int b = blockIdx.y;
  const int t0 = blockIdx.x * KBINS;
  const int* ab = a_ws + (size_t)b * (T + 1);
  const size_t bS = (size_t)b * S;
  const int c4 = threadIdx.x * 4;

  int bound[KBINS + 1];
#pragma unroll
  for (int k = 0; k <= KBINS; ++k) bound[k] = ab[min(t0 + k, T)];

#pragma unroll
  for (int k = 0; k < KBINS; ++k) {
    const int t = t0 + k;
    if (t >= T) break;
    const int st = bound[k];
    const int en = min(bound[k + 1], S - 1);
    fvec4 acc = (fvec4)0.0f;
    float d = 0.0f;
    for (int s = (st < 0 ? 0 : st); s <= en; ++s) {
      const float coeff = (s == st) ? rw[bS + s] : lw[bS + s];
      d = d + (coeff * (float)(s + 1)) / FT;
      const fvec4 v = *reinterpret_cast<const fvec4*>(in + (bS + s) * (size_t)C + c4);
      acc += coeff * v;
    }
    __builtin_nontemporal_store(acc,
        reinterpret_cast<fvec4*>(out + ((size_t)b * T + t) * (size_t)C + c4));
    if (threadIdx.x == 0)
      __builtin_nontemporal_store(d, &o_delay[(size_t)b * T + t]);
  }

  // dur for this block's bins (1 thread per bin)
  if (threadIdx.x < KBINS) {
    const int t = t0 + threadIdx.x;
    if (t < T) {
      const int seq0 = hdr_g[b * 4 + 0];
      const int m    = hdr_g[b * 4 + 1];
      const int L    = hdr_g[b * 4 + 2];
      const int adj  = hdr_g[b * 4 + 3];
      int dv = (t < m) ? hist_g[(size_t)b * (T + 1) + seq0 + t] : 0;
      if (t == L - 1) dv += adj;
      __builtin_nontemporal_store((float)dv, &o_dur[(size_t)b * T + t]);
    }
  }
}

extern "C" void kernel_launch(void* const* d_in, const int* in_sizes, int n_in,
                              void* d_out, int out_size, void* d_ws, size_t ws_size,
                              hipStream_t stream)
{
  const float* inp = (const float*)d_in[0];
  const float* iw  = (const float*)d_in[1];
  const unsigned char* mask = (const unsigned char*)d_in[2];
  const int* tl = (const int*)d_in[3];
  const int B = in_sizes[3];
  const int S = in_sizes[1] / B;
  const int C = in_sizes[0] / in_sizes[1];
  const long long T = ((long long)out_size - B - 2LL * B * S) / ((long long)B * C + 2LL * B);

  float* o = (float*)d_out;
  float* o_out   = o;
  float* o_delay = o_out + (size_t)B * T * C;
  float* o_dur   = o_delay + (size_t)B * T;
  float* o_wsum  = o_dur + (size_t)B * T;
  float* o_rw    = o_wsum + B;
  float* o_lw    = o_rw + (size_t)B * S;

  int* a_ws   = (int*)d_ws;                      // B*(T+1)
  int* hist_g = a_ws + (size_t)B * (T + 1);      // B*(T+1)
  int* hdr_g  = hist_g + (size_t)B * (T + 1);    // B*4

  size_t smem = (size_t)(2 * S + 64) * sizeof(float) + 2 * (size_t)(T + 1) * sizeof(int);
  if (S == 2048 && T == 512) {
    hipLaunchKernelGGL((cif_row_kernel<2048, 512>), dim3(B), dim3(512), smem, stream,
                       iw, mask, tl, o_wsum, o_rw, o_lw, a_ws, hist_g, hdr_g, S, (int)T);
  } else {
    hipLaunchKernelGGL((cif_row_kernel<0, 0>), dim3(B), dim3(512), smem, stream,
                       iw, mask, tl, o_wsum, o_rw, o_lw, a_ws, hist_g, hdr_g, S, (int)T);
  }
  dim3 g2((unsigned)((T + KBINS - 1) / KBINS), (unsigned)B);
  hipLaunchKernelGGL(cif_gather_kernel, g2, dim3(C / 4), 0, stream,
                     inp, o_rw, o_lw, a_ws, hist_g, hdr_g, o_out, o_delay, o_dur,
                     S, (int)T, C);
}